// Round 11
// baseline (268.222 us; speedup 1.0000x reference)
//
#include <hip/hip_runtime.h>
#include <hip/hip_bf16.h>

#define BB 2
#define SS 2048
#define DIMM 1024
#define HH 16
#define DKK 64
// 0.125 (1/sqrt(DK)) * log2(e): folded into Q so softmax uses raw v_exp_f32 (2^x)
#define QSCALE 0.18033688011112042592f

using bf16 = __hip_bfloat16;
typedef __attribute__((ext_vector_type(8))) short v8s;
typedef __attribute__((ext_vector_type(4))) short v4s;
typedef __attribute__((ext_vector_type(4))) float f32x4;
typedef __attribute__((ext_vector_type(16))) float f32x16;

using lds_u32 = __attribute__((address_space(3))) unsigned int;
using glb_u32 = const __attribute__((address_space(1))) unsigned int;

// async global->LDS, 16B per lane.  LDS dest is WAVE-UNIFORM base (HW adds
// lane*16); global src is per-lane.
__device__ __forceinline__ void gload16(void* lds, const void* g) {
  __builtin_amdgcn_global_load_lds((glb_u32*)g, (lds_u32*)lds, 16, 0, 0);
}

__device__ __forceinline__ void cvt4(const float* __restrict__ s,
                                     bf16* __restrict__ d, int idx) {
  const float4 f = ((const float4*)s)[idx];
  bf16 t[4] = {__float2bfloat16(f.x), __float2bfloat16(f.y),
               __float2bfloat16(f.z), __float2bfloat16(f.w)};
  *(v4s*)(d + (size_t)idx * 4) = *(const v4s*)t;
}

__device__ __forceinline__ int cvt_pk_bf16(float lo, float hi) {
  int r;
  asm("v_cvt_pk_bf16_f32 %0, %1, %2" : "=v"(r) : "v"(lo), "v"(hi));
  return r;
}

// ---------------------------------------------------------------------------
// Fused fp32->bf16 conversion (dec, enc, Wq, Wkv, Wo) + mask bit-packing.
// Mask packed as mp[b][kt][q] (q contiguous) so attn's per-lane-q load is
// coalesced.  Wo converted with PERMUTED columns (see out_gemm).
// ---------------------------------------------------------------------------
__global__ __launch_bounds__(256) void convert_pack_kernel(
    const float* __restrict__ dec, const float* __restrict__ enc,
    const float* __restrict__ Wq, const float* __restrict__ Wkv,
    const float* __restrict__ Wo, const int* __restrict__ mask,
    bf16* __restrict__ decb, bf16* __restrict__ encb, bf16* __restrict__ Wqb,
    bf16* __restrict__ Wkvb, bf16* __restrict__ Wob,
    unsigned long long* __restrict__ mp) {
  const int gid = blockIdx.x * 256 + threadIdx.x;  // 0..262143
  const int NT = 256 * 1024;
#pragma unroll
  for (int i = 0; i < 4; ++i) cvt4(dec, decb, gid + i * NT);
#pragma unroll
  for (int i = 0; i < 4; ++i) cvt4(enc, encb, gid + i * NT);
  cvt4(Wq, Wqb, gid);
#pragma unroll
  for (int i = 0; i < 2; ++i) cvt4(Wkv, Wkvb, gid + i * NT);
  // Wo with column permutation c' = h*64+d  <-  c = d*16+h
  {
    const int n = gid >> 8;          // row 0..1023
    const int c4 = (gid & 255) * 4;  // dest col base (4 consecutive d)
    const int h = c4 >> 6, d0 = c4 & 63;
    const float* src = Wo + (size_t)n * DIMM + h;
    bf16 t[4];
#pragma unroll
    for (int i2 = 0; i2 < 4; ++i2)
      t[i2] = __float2bfloat16(src[(d0 + i2) * 16]);
    *(v4s*)(Wob + (size_t)n * DIMM + c4) = *(const v4s*)t;
  }
  const int lane = threadIdx.x & 63;
  const int wave_id = gid >> 6;  // 0..4095
  for (int i = 0; i < 32; ++i) {
    const size_t w = (size_t)wave_id * 32 + i;
    const unsigned long long bm = __ballot(mask[w * 64 + lane] != 0);
    if (lane == 0) {
      const int bb = (int)(w >> 16);        // batch
      const int qq = (int)((w >> 5) & 2047);  // q row
      const int kc = (int)(w & 31);         // k chunk
      mp[((size_t)bb * 32 + kc) * SS + qq] = bm;
    }
  }
}

// ---------------------------------------------------------------------------
// Merged projection GEMM v3: global_load_lds dbuf pipeline with CROSS-TILE
// prefetch (stage t+1 issued BEFORE computing t; ONE barrier/step).  R6's
// gload attempt failed because it drained vmcnt immediately after issue
// (stage -> barrier -> compute: zero overlap); this is the m97 ordering
// (517 -> 874 TF on the ladder).  Linear LDS [2][128][64] (gload dest must
// be linear; m97 carried the resulting conflicts at 874 TF).  Keeps R9's
// T1 XCD remap (1D grid 768, g-siblings of one A-panel share an XCD L2).
// ---------------------------------------------------------------------------
__global__ __launch_bounds__(256) void proj_gemm_kernel(
    const bf16* __restrict__ decb, const bf16* __restrict__ encb,
    const bf16* __restrict__ Wqb, const bf16* __restrict__ Wkvb,
    bf16* __restrict__ Qr, bf16* __restrict__ Kr, bf16* __restrict__ Vt) {
  __shared__ __align__(16) bf16 As[2][128][64];
  __shared__ __align__(16) bf16 Bs[2][128][64];
  const int t = threadIdx.x;
  const int wave = t >> 6, lane = t & 63;
  const int quad = lane >> 4, l15 = lane & 15;
  const int wm = (wave >> 1) * 64, wn = (wave & 1) * 64;

  const int bid = blockIdx.x;
  const int xcd = bid & 7, slot = bid >> 3;  // slot 0..95
  const int km = xcd + 8 * (slot >> 3);      // (kind,m0) id 0..95
  const int g = slot & 7;                    // 128-col group (2 heads)
  const int kind = km >> 5;                  // 0=Q, 1=K, 2=V
  const int m0 = (km & 31) * 128;

  // staging geometry: chunk = wave*4 + j covers LDS rows [chunk*8, +8);
  // lane i -> row chunk*8 + (i>>3), col (i&7)*8 (matches linear lane*16B).
  const int lrow = lane >> 3;
  const int lcol = (lane & 7) * 8;

  const bf16* aptr[4];
  const bf16* bptr[4];
#pragma unroll
  for (int j = 0; j < 4; ++j) {
    const int r = (wave * 4 + j) * 8 + lrow;          // LDS row 0..127
    const int pw = (r & 63) * 16 + g * 2 + (r >> 6);  // permuted W row
    if (kind == 0) {
      aptr[j] = decb + (size_t)(m0 + r) * DIMM + lcol;
      bptr[j] = Wqb + (size_t)pw * DIMM + lcol;
    } else if (kind == 1) {
      aptr[j] = encb + (size_t)(m0 + r) * DIMM + lcol;
      bptr[j] = Wkvb + (size_t)pw * DIMM + lcol;
    } else {
      aptr[j] = Wkvb + (size_t)(pw + DIMM) * DIMM + lcol;
      bptr[j] = encb + (size_t)(m0 + r) * DIMM + lcol;
    }
  }

  auto stage = [&](int kc, int buf) {
#pragma unroll
    for (int j = 0; j < 4; ++j) {
      gload16(&As[buf][(wave * 4 + j) * 8][0], aptr[j] + kc);
      gload16(&Bs[buf][(wave * 4 + j) * 8][0], bptr[j] + kc);
    }
  };

  f32x4 acc[4][4] = {};
  stage(0, 0);

  for (int kt = 0; kt < 16; ++kt) {
    const int cb = kt & 1;
    __syncthreads();  // drains stage(kt); guards buf[cb^1] reuse
    if (kt < 15) stage((kt + 1) * 64, cb ^ 1);  // in flight under compute
#pragma unroll
    for (int ks = 0; ks < 2; ++ks) {
      v8s af[4], bfr[4];
#pragma unroll
      for (int i = 0; i < 4; ++i)
        af[i] = *(const v8s*)&As[cb][wm + i * 16 + l15][ks * 32 + quad * 8];
#pragma unroll
      for (int j = 0; j < 4; ++j)
        bfr[j] = *(const v8s*)&Bs[cb][wn + j * 16 + l15][ks * 32 + quad * 8];
#pragma unroll
      for (int i = 0; i < 4; ++i)
#pragma unroll
        for (int j = 0; j < 4; ++j)
          acc[i][j] = __builtin_amdgcn_mfma_f32_16x16x32_bf16(
              af[i], bfr[j], acc[i][j], 0, 0, 0);
    }
  }

#pragma unroll
  for (int i = 0; i < 4; ++i) {
#pragma unroll
    for (int r = 0; r < 4; ++r) {
      const int mm = wm + i * 16 + quad * 4 + r;  // tile-m 0..127
#pragma unroll
      for (int j = 0; j < 4; ++j) {
        const int nn = wn + j * 16 + l15;  // tile-n 0..127
        const float v = acc[i][j][r];
        if (kind == 0) {
          Qr[(size_t)(m0 + mm) * DIMM + g * 128 + nn] =
              __float2bfloat16(v * QSCALE);
        } else if (kind == 1) {
          Kr[(size_t)(m0 + mm) * DIMM + g * 128 + nn] = __float2bfloat16(v);
        } else {
          const int h = g * 2 + (mm >> 6), d = mm & 63;
          const int sn = m0 + nn;
          const int b = sn >> 11, s = sn & (SS - 1);
          Vt[(((size_t)b * HH + h) * DKK + d) * SS + s] = __float2bfloat16(v);
        }
      }
    }
  }
}

// ---------------------------------------------------------------------------
// Output projection GEMM v3: same gload-dbuf pipeline, tile widened to
// 128x128 (same body as proj; double the B-reuse vs the old 128x64).
// Grid 256, T1 XCD remap: the 8 n-siblings of each m-panel (shared A rows)
// land on one XCD.  Bijective: 256 = 8 * 32.  out = Ar @ Wob^T.
// ---------------------------------------------------------------------------
__global__ __launch_bounds__(256) void out_gemm_kernel(
    const bf16* __restrict__ A, const bf16* __restrict__ W,
    float* __restrict__ out) {
  __shared__ __align__(16) bf16 As[2][128][64];
  __shared__ __align__(16) bf16 Bs[2][128][64];
  const int t = threadIdx.x;
  const int wave = t >> 6, lane = t & 63;
  const int quad = lane >> 4, l15 = lane & 15;
  const int wm = (wave >> 1) * 64, wn = (wave & 1) * 64;

  const int bid = blockIdx.x;
  const int xcd = bid & 7, slot = bid >> 3;      // slot 0..31
  const int m0 = (xcd + 8 * (slot >> 3)) * 128;  // 32 m-panels over 8 XCDs
  const int n0 = (slot & 7) * 128;

  const int lrow = lane >> 3;
  const int lcol = (lane & 7) * 8;

  const bf16* aptr[4];
  const bf16* bptr[4];
#pragma unroll
  for (int j = 0; j < 4; ++j) {
    const int r = (wave * 4 + j) * 8 + lrow;
    aptr[j] = A + (size_t)(m0 + r) * DIMM + lcol;
    bptr[j] = W + (size_t)(n0 + r) * DIMM + lcol;
  }

  auto stage = [&](int kc, int buf) {
#pragma unroll
    for (int j = 0; j < 4; ++j) {
      gload16(&As[buf][(wave * 4 + j) * 8][0], aptr[j] + kc);
      gload16(&Bs[buf][(wave * 4 + j) * 8][0], bptr[j] + kc);
    }
  };

  f32x4 acc[4][4] = {};
  stage(0, 0);

  for (int kt = 0; kt < 16; ++kt) {
    const int cb = kt & 1;
    __syncthreads();
    if (kt < 15) stage((kt + 1) * 64, cb ^ 1);
#pragma unroll
    for (int ks = 0; ks < 2; ++ks) {
      v8s af[4], bfr[4];
#pragma unroll
      for (int i = 0; i < 4; ++i)
        af[i] = *(const v8s*)&As[cb][wm + i * 16 + l15][ks * 32 + quad * 8];
#pragma unroll
      for (int j = 0; j < 4; ++j)
        bfr[j] = *(const v8s*)&Bs[cb][wn + j * 16 + l15][ks * 32 + quad * 8];
#pragma unroll
      for (int i = 0; i < 4; ++i)
#pragma unroll
        for (int j = 0; j < 4; ++j)
          acc[i][j] = __builtin_amdgcn_mfma_f32_16x16x32_bf16(
              af[i], bfr[j], acc[i][j], 0, 0, 0);
    }
  }

#pragma unroll
  for (int i = 0; i < 4; ++i) {
#pragma unroll
    for (int r = 0; r < 4; ++r) {
      const int m = m0 + wm + i * 16 + quad * 4 + r;
#pragma unroll
      for (int j = 0; j < 4; ++j) {
        const int n = n0 + wn + j * 16 + l15;
        out[(size_t)m * DIMM + n] = acc[i][j][r];
      }
    }
  }
}

// ---------------------------------------------------------------------------
// MFMA flash attention v7 EXACT (best measured: 56.5-57.4us).  R4/R5/R7/R8
// all regressed it; do not touch the inner loop.
// ---------------------------------------------------------------------------
__global__ __launch_bounds__(512) void attn_kernel(
    const bf16* __restrict__ Qr, const bf16* __restrict__ Kr,
    const bf16* __restrict__ Vt, const unsigned long long* __restrict__ mp,
    bf16* __restrict__ Ar) {
  // smem[0] = K tiles, smem[1] = V tiles; [kv][parity][buf][row][col]
  __shared__ __align__(16) bf16 smem[2][2][2][64][72];

  const int t = threadIdx.x;
  const int wave = t >> 6, lane = t & 63;
  const int l31 = lane & 31, hf = lane >> 5;
  const int qb = wave & 3;   // q sub-block 0..3 (32 rows each)
  const int pr = wave >> 2;  // kt parity: 0 = even kt, 1 = odd kt

  const int bx = blockIdx.x;
  const int xcd = bx & 7, j = bx >> 3;
  const int g = (xcd << 2) | (j & 3);  // (b,h) group 0..31
  const int tile = j >> 2;             // q-tile 0..15 (128 rows each)
  const int hd = g & 15, b = g >> 4;

  const int qw = tile * 128 + qb * 32;  // wave owns 32 q-rows
  const size_t bhv = ((size_t)b * HH + hd) * DKK;

  // Q as B-fragments: lane l31 = q-col, c = cs*16 + 8*hf + i
  v8s bq[4];
  {
    const bf16* qrow = Qr + ((size_t)(b * SS + qw + l31)) * DIMM + hd * 64;
#pragma unroll
    for (int cs = 0; cs < 4; ++cs)
      bq[cs] = *(const v8s*)(qrow + cs * 16 + 8 * hf);
  }

  // ones B-fragment for row-sum MFMA
  v8s vones;
#pragma unroll
  for (int i = 0; i < 8; ++i) vones[i] = (short)0x3F80;

  f32x16 o0 = {}, o1 = {}, ol = {};

  // cooperative staging: 512 threads x 16B per tile, 4 tiles per step
  const int r0 = t >> 3;       // 0..63
  const int c0 = (t & 7) * 8;  // 0..56

  auto gK = [&](int kt) {
    return *(const v8s*)(Kr + ((size_t)(b * SS + kt * 64 + r0)) * DIMM +
                         hd * 64 + c0);
  };
  auto gV = [&](int kt) {
    return *(const v8s*)(Vt + (bhv + r0) * SS + kt * 64 + c0);
  };
  auto loadM = [&](int kt) {
    return mp[((size_t)b * 32 + kt) * SS + qw + l31];
  };

  // prologue: stage kt 0 (par0 buf0) and kt 1 (par1 buf0); prefetch kt 2,3
  {
    const v8s k0 = gK(0), v0 = gV(0), k1 = gK(1), v1 = gV(1);
    *(v8s*)&smem[0][0][0][r0][c0] = k0;
    *(v8s*)&smem[1][0][0][r0][c0] = v0;
    *(v8s*)&smem[0][1][0][r0][c0] = k1;
    *(v8s*)&smem[1][1][0][r0][c0] = v1;
  }
  v8s kpr[2], vpr[2];
  kpr[0] = gK(2);
  vpr[0] = gV(2);
  kpr[1] = gK(3);
  vpr[1] = gV(3);
  unsigned long long mwcur = loadM(pr);

  for (int s = 0; s < 16; ++s) {
    __syncthreads();
    const int nb = (s + 1) & 1;
    if (s < 15) {
      *(v8s*)&smem[0][0][nb][r0][c0] = kpr[0];
      *(v8s*)&smem[1][0][nb][r0][c0] = vpr[0];
      *(v8s*)&smem[0][1][nb][r0][c0] = kpr[1];
      *(v8s*)&smem[1][1][nb][r0][c0] = vpr[1];
      if (s < 14) {
        kpr[0] = gK(2 * s + 4);
        vpr[0] = gV(2 * s + 4);
        kpr[1] = gK(2 * s + 5);
        vpr[1] = gV(2 * s + 5);
      }
    }
    const unsigned long long mwnext = (s < 15) ? loadM(2 * s + 2 + pr) : 0ULL;
    const unsigned long long mq = mwcur >> (4 * hf);
    const int cb = s & 1;

    // ---- QK^T (swapped): st[n] rows = k (n*32 block), col = q = l31 ----
    f32x16 st[2];
#pragma unroll
    for (int n = 0; n < 2; ++n) {
      f32x16 sa = {};
#pragma unroll
      for (int cs = 0; cs < 4; ++cs) {
        const v8s ak =
            *(const v8s*)&smem[0][pr][cb][n * 32 + l31][cs * 16 + 8 * hf];
        sa = __builtin_amdgcn_mfma_f32_32x32x16_bf16(ak, bq[cs], sa, 0, 0, 0);
      }
      st[n] = sa;
    }

    // ---- masked exp2 + pack to bf16 pairs (in-register) ----
    int pd[8][2];
#pragma unroll
    for (int n = 0; n < 2; ++n)
#pragma unroll
      for (int g2 = 0; g2 < 4; ++g2)
#pragma unroll
        for (int jj = 0; jj < 2; ++jj) {
          const int bp = 32 * n + 8 * g2 + 2 * jj;
          const int m = g2 * 4 + 2 * jj;
          const float p0 =
              ((mq >> bp) & 1) ? __builtin_amdgcn_exp2f(st[n][m]) : 0.f;
          const float p1 =
              ((mq >> (bp + 1)) & 1) ? __builtin_amdgcn_exp2f(st[n][m + 1])
                                     : 0.f;
          pd[n * 4 + g2][jj] = cvt_pk_bf16(p0, p1);
        }

    // ---- redistribute to PV A-fragments: 2 permlane32_swap per k-slice ----
    v8s af[4];
#pragma unroll
    for (int ks = 0; ks < 4; ++ks) {
      int a0 = pd[2 * ks][0], b0 = pd[2 * ks + 1][0];
      int a1 = pd[2 * ks][1], b1 = pd[2 * ks + 1][1];
      asm("v_permlane32_swap_b32 %0, %1" : "+v"(a0), "+v"(b0));
      asm("v_permlane32_swap_b32 %0, %1" : "+v"(a1), "+v"(b1));
      int4 w;
      w.x = a0;
      w.y = a1;
      w.z = b0;
      w.w = b1;
      af[ks] = *(v8s*)&w;
    }

    // ---- PV + row-sum ----
#pragma unroll
    for (int ks = 0; ks < 4; ++ks) {
      const v8s bv0 = *(const v8s*)&smem[1][pr][cb][l31][ks * 16 + 8 * hf];
      const v8s bv1 =
          *(const v8s*)&smem[1][pr][cb][32 + l31][ks * 16 + 8 * hf];
      o0 = __builtin_amdgcn_mfma_f32_32x32x16_bf16(af[ks], bv0, o0, 0, 0, 0);
      o1 = __builtin_amdgcn_mfma_f32_32x32x16_bf16(af[ks], bv1, o1, 0, 0, 0);
      ol = __builtin_amdgcn_mfma_f32_32x32x16_bf16(af[ks], vones, ol, 0, 0, 0);
    }
    mwcur = mwnext;
  }

  // ---- cross-parity combine via LDS (exact sum; no running max) ----
  // scratch overlays the (now dead) K/V staging; stride 52 f32 (16B-aligned,
  // 8-bank spread) per lane.
  __syncthreads();
  float* scratch = (float*)&smem[0][0][0][0][0];
  if (wave >= 4) {
    float* dst = scratch + ((size_t)(wave - 4) * 64 + lane) * 52;
#pragma unroll
    for (int i = 0; i < 4; ++i) {
      f32x4 t0 = {o0[4 * i], o0[4 * i + 1], o0[4 * i + 2], o0[4 * i + 3]};
      f32x4 t1 = {o1[4 * i], o1[4 * i + 1], o1[4 * i + 2], o1[4 * i + 3]};
      f32x4 t2 = {ol[4 * i], ol[4 * i + 1], ol[4 * i + 2], ol[4 * i + 3]};
      *(f32x4*)(dst + 4 * i) = t0;
      *(f32x4*)(dst + 16 + 4 * i) = t1;
      *(f32x4*)(dst + 32 + 4 * i) = t2;
    }
  }
  __syncthreads();
  if (wave < 4) {
    const float* src = scratch + ((size_t)wave * 64 + lane) * 52;
#pragma unroll
    for (int m = 0; m < 16; ++m) {
      o0[m] += src[m];
      o1[m] += src[16 + m];
      ol[m] += src[32 + m];
    }
    // ---- epilogue: normalize rows and store flat [q][hd*64 + d] ----
#pragma unroll
    for (int m = 0; m < 16; ++m) {
      const float inv = __builtin_amdgcn_rcpf(ol[m]);
      const int q = qw + (m & 3) + 8 * (m >> 2) + 4 * hf;
      const size_t row = (size_t)b * SS + q;
      Ar[row * DIMM + hd * 64 + l31] = __float2bfloat16(o0[m] * inv);
      Ar[row * DIMM + hd * 64 + 32 + l31] = __float2bfloat16(o1[m] * inv);
    }
  }
}

extern "C" void kernel_launch(void* const* d_in, const int* in_sizes, int n_in,
                              void* d_out, int out_size, void* d_ws,
                              size_t ws_size, hipStream_t stream) {
  const float* dec = (const float*)d_in[0];
  const float* enc = (const float*)d_in[1];
  const float* Wq = (const float*)d_in[2];
  const float* Wkv = (const float*)d_in[3];
  const float* Wo = (const float*)d_in[4];
  const int* mask = (const int*)d_in[5];
  float* out = (float*)d_out;

  // decb/Wqb live in d_out: dead scratch until out_gemm overwrites it.
  bf16* decb = (bf16*)d_out;
  bf16* Wqb = (bf16*)((char*)d_out + ((size_t)2 * SS * DIMM * 2));

  // ws layout (40.4 MB): encb 8 MiB (Ar overlays) | Wkvb 4 | Wob 2 |
  // Qr 8 | Kr 8 | Vt 8 | mp 1
  char* ws = (char*)d_ws;
  size_t off = 0;
  bf16* encb = (bf16*)(ws + off);
  bf16* Ar = (bf16*)(ws + off);   off += (size_t)2 * SS * DIMM * 2;
  bf16* Wkvb = (bf16*)(ws + off); off += (size_t)2 * DIMM * DIMM * 2;
  bf16* Wob = (bf16*)(ws + off);  off += (size_t)DIMM * DIMM * 2;
  bf16* Qr = (bf16*)(ws + off);   off += (size_t)2 * SS * DIMM * 2;
  bf16* Kr = (bf16*)(ws + off);   off += (size_t)2 * SS * DIMM * 2;
  bf16* Vt = (bf16*)(ws + off);   off += (size_t)2 * SS * DIMM * 2;
  unsigned long long* mp = (unsigned long long*)(ws + off);

  dim3 blk(256);
  convert_pack_kernel<<<dim3(1024), blk, 0, stream>>>(
      dec, enc, Wq, Wkv, Wo, mask, decb, encb, Wqb, Wkvb, Wob, mp);
  proj_gemm_kernel<<<dim3(768), blk, 0, stream>>>(decb, encb, Wqb, Wkvb, Qr,
                                                  Kr, Vt);
  attn_kernel<<<dim3(512), dim3(512), 0, stream>>>(Qr, Kr, Vt, mp, Ar);
  out_gemm_kernel<<<dim3(256), blk, 0, stream>>>(Ar, Wob, out);
}

// Round 12
// 242.372 us; speedup vs baseline: 1.1067x; 1.1067x over previous
//
#include <hip/hip_runtime.h>
#include <hip/hip_bf16.h>

#define BB 2
#define SS 2048
#define DIMM 1024
#define HH 16
#define DKK 64
// 0.125 (1/sqrt(DK)) * log2(e): folded into Q so softmax uses raw v_exp_f32 (2^x)
#define QSCALE 0.18033688011112042592f

using bf16 = __hip_bfloat16;
typedef __attribute__((ext_vector_type(8))) short v8s;
typedef __attribute__((ext_vector_type(4))) short v4s;
typedef __attribute__((ext_vector_type(4))) float f32x4;
typedef __attribute__((ext_vector_type(16))) float f32x16;

using lds_u32 = __attribute__((address_space(3))) unsigned int;
using glb_u32 = const __attribute__((address_space(1))) unsigned int;

// async global->LDS, 16B per lane.  LDS dest is WAVE-UNIFORM base (HW adds
// lane*16); global src is per-lane.
__device__ __forceinline__ void gload16(void* lds, const void* g) {
  __builtin_amdgcn_global_load_lds((glb_u32*)g, (lds_u32*)lds, 16, 0, 0);
}

__device__ __forceinline__ void cvt4(const float* __restrict__ s,
                                     bf16* __restrict__ d, int idx) {
  const float4 f = ((const float4*)s)[idx];
  bf16 t[4] = {__float2bfloat16(f.x), __float2bfloat16(f.y),
               __float2bfloat16(f.z), __float2bfloat16(f.w)};
  *(v4s*)(d + (size_t)idx * 4) = *(const v4s*)t;
}

__device__ __forceinline__ int cvt_pk_bf16(float lo, float hi) {
  int r;
  asm("v_cvt_pk_bf16_f32 %0, %1, %2" : "=v"(r) : "v"(lo), "v"(hi));
  return r;
}

// ---------------------------------------------------------------------------
// Fused fp32->bf16 conversion (dec, enc, Wq, Wkv, Wo) + mask bit-packing.
// ---------------------------------------------------------------------------
__global__ __launch_bounds__(256) void convert_pack_kernel(
    const float* __restrict__ dec, const float* __restrict__ enc,
    const float* __restrict__ Wq, const float* __restrict__ Wkv,
    const float* __restrict__ Wo, const int* __restrict__ mask,
    bf16* __restrict__ decb, bf16* __restrict__ encb, bf16* __restrict__ Wqb,
    bf16* __restrict__ Wkvb, bf16* __restrict__ Wob,
    unsigned long long* __restrict__ mp) {
  const int gid = blockIdx.x * 256 + threadIdx.x;  // 0..262143
  const int NT = 256 * 1024;
#pragma unroll
  for (int i = 0; i < 4; ++i) cvt4(dec, decb, gid + i * NT);
#pragma unroll
  for (int i = 0; i < 4; ++i) cvt4(enc, encb, gid + i * NT);
  cvt4(Wq, Wqb, gid);
#pragma unroll
  for (int i = 0; i < 2; ++i) cvt4(Wkv, Wkvb, gid + i * NT);
  // Wo with column permutation c' = h*64+d  <-  c = d*16+h
  {
    const int n = gid >> 8;          // row 0..1023
    const int c4 = (gid & 255) * 4;  // dest col base (4 consecutive d)
    const int h = c4 >> 6, d0 = c4 & 63;
    const float* src = Wo + (size_t)n * DIMM + h;
    bf16 t[4];
#pragma unroll
    for (int i2 = 0; i2 < 4; ++i2)
      t[i2] = __float2bfloat16(src[(d0 + i2) * 16]);
    *(v4s*)(Wob + (size_t)n * DIMM + c4) = *(const v4s*)t;
  }
  const int lane = threadIdx.x & 63;
  const int wave_id = gid >> 6;  // 0..4095
  for (int i = 0; i < 32; ++i) {
    const size_t w = (size_t)wave_id * 32 + i;
    const unsigned long long bm = __ballot(mask[w * 64 + lane] != 0);
    if (lane == 0) {
      const int bb = (int)(w >> 16);        // batch
      const int qq = (int)((w >> 5) & 2047);  // q row
      const int kc = (int)(w & 31);         // k chunk
      mp[((size_t)bb * 32 + kc) * SS + qq] = bm;
    }
  }
}

// ---------------------------------------------------------------------------
// Merged projection GEMM v4: gload dbuf pipeline + SOURCE-SIDE XOR SWIZZLE
// (rule #21 both-sides-or-neither).  R11's linear [128][64] LDS made the
// fragment read a 16-way bank conflict (row stride 128B = 32 banks; 9.4M
// conflict cycles, 65us).  Fix per m173/m201: LDS dest stays linear (gload
// requirement); the per-lane GLOBAL col is pre-swizzled so 16B block (r,c')
// holds global block c'^(r&7); reads apply the same XOR -> 2-way (free).
//   stage lane col = ((lane&7) ^ (lane>>3)) * 8
//   read col       = (((ks*4+quad) ^ (l15&7)) * 8)
// Cross-tile prefetch (stage t+1 before compute t, ONE barrier/step) and
// R9's T1 XCD remap kept.
// ---------------------------------------------------------------------------
__global__ __launch_bounds__(256) void proj_gemm_kernel(
    const bf16* __restrict__ decb, const bf16* __restrict__ encb,
    const bf16* __restrict__ Wqb, const bf16* __restrict__ Wkvb,
    bf16* __restrict__ Qr, bf16* __restrict__ Kr, bf16* __restrict__ Vt) {
  __shared__ __align__(16) bf16 As[2][128][64];
  __shared__ __align__(16) bf16 Bs[2][128][64];
  const int t = threadIdx.x;
  const int wave = t >> 6, lane = t & 63;
  const int quad = lane >> 4, l15 = lane & 15;
  const int wm = (wave >> 1) * 64, wn = (wave & 1) * 64;

  const int bid = blockIdx.x;
  const int xcd = bid & 7, slot = bid >> 3;  // slot 0..95
  const int km = xcd + 8 * (slot >> 3);      // (kind,m0) id 0..95
  const int g = slot & 7;                    // 128-col group (2 heads)
  const int kind = km >> 5;                  // 0=Q, 1=K, 2=V
  const int m0 = (km & 31) * 128;

  // staging: chunk = wave*4 + j covers LDS rows [chunk*8, +8); lane ->
  // row chunk*8 + (lane>>3), linear block lane&7.  SOURCE col swizzled so
  // LDS block (r, c') holds global block c' ^ (r&7).
  const int lrow = lane >> 3;
  const int lcol = ((lane & 7) ^ lrow) * 8;  // pre-swizzled global col

  const bf16* aptr[4];
  const bf16* bptr[4];
#pragma unroll
  for (int j = 0; j < 4; ++j) {
    const int r = (wave * 4 + j) * 8 + lrow;          // LDS row 0..127
    const int pw = (r & 63) * 16 + g * 2 + (r >> 6);  // permuted W row
    if (kind == 0) {
      aptr[j] = decb + (size_t)(m0 + r) * DIMM + lcol;
      bptr[j] = Wqb + (size_t)pw * DIMM + lcol;
    } else if (kind == 1) {
      aptr[j] = encb + (size_t)(m0 + r) * DIMM + lcol;
      bptr[j] = Wkvb + (size_t)pw * DIMM + lcol;
    } else {
      aptr[j] = Wkvb + (size_t)(pw + DIMM) * DIMM + lcol;
      bptr[j] = encb + (size_t)(m0 + r) * DIMM + lcol;
    }
  }

  auto stage = [&](int kc, int buf) {
#pragma unroll
    for (int j = 0; j < 4; ++j) {
      gload16(&As[buf][(wave * 4 + j) * 8][0], aptr[j] + kc);
      gload16(&Bs[buf][(wave * 4 + j) * 8][0], bptr[j] + kc);
    }
  };

  f32x4 acc[4][4] = {};
  stage(0, 0);

  for (int kt = 0; kt < 16; ++kt) {
    const int cb = kt & 1;
    __syncthreads();  // drains stage(kt); guards buf[cb^1] reuse
    if (kt < 15) stage((kt + 1) * 64, cb ^ 1);  // in flight under compute
#pragma unroll
    for (int ks = 0; ks < 2; ++ks) {
      // swizzled read col: block (ks*4+quad) ^ (row&7), row&7 == l15&7
      const int rc = (((ks * 4 + quad) ^ (l15 & 7)) * 8);
      v8s af[4], bfr[4];
#pragma unroll
      for (int i = 0; i < 4; ++i)
        af[i] = *(const v8s*)&As[cb][wm + i * 16 + l15][rc];
#pragma unroll
      for (int j = 0; j < 4; ++j)
        bfr[j] = *(const v8s*)&Bs[cb][wn + j * 16 + l15][rc];
#pragma unroll
      for (int i = 0; i < 4; ++i)
#pragma unroll
        for (int j = 0; j < 4; ++j)
          acc[i][j] = __builtin_amdgcn_mfma_f32_16x16x32_bf16(
              af[i], bfr[j], acc[i][j], 0, 0, 0);
    }
  }

#pragma unroll
  for (int i = 0; i < 4; ++i) {
#pragma unroll
    for (int r = 0; r < 4; ++r) {
      const int mm = wm + i * 16 + quad * 4 + r;  // tile-m 0..127
#pragma unroll
      for (int j = 0; j < 4; ++j) {
        const int nn = wn + j * 16 + l15;  // tile-n 0..127
        const float v = acc[i][j][r];
        if (kind == 0) {
          Qr[(size_t)(m0 + mm) * DIMM + g * 128 + nn] =
              __float2bfloat16(v * QSCALE);
        } else if (kind == 1) {
          Kr[(size_t)(m0 + mm) * DIMM + g * 128 + nn] = __float2bfloat16(v);
        } else {
          const int h = g * 2 + (mm >> 6), d = mm & 63;
          const int sn = m0 + nn;
          const int b = sn >> 11, s = sn & (SS - 1);
          Vt[(((size_t)b * HH + h) * DKK + d) * SS + s] = __float2bfloat16(v);
        }
      }
    }
  }
}

// ---------------------------------------------------------------------------
// Output projection GEMM (R9 reg-staged version -- measured best config):
// out = Ar @ Wob^T, tile 128m x 64n, BK=64, padded LDS, T1 XCD remap
// (grid 512; 16 n-siblings of each m-panel share one XCD).
// ---------------------------------------------------------------------------
__global__ __launch_bounds__(256) void out_gemm_kernel(
    const bf16* __restrict__ A, const bf16* __restrict__ W,
    float* __restrict__ out) {
  __shared__ __align__(16) bf16 As[128][72];
  __shared__ __align__(16) bf16 Bs[64][72];
  const int t = threadIdx.x;
  const int wave = t >> 6, lane = t & 63;
  const int quad = lane >> 4, l15 = lane & 15;
  const int wm = (wave >> 1) * 64, wn = (wave & 1) * 32;

  const int bid = blockIdx.x;
  const int xcd = bid & 7, slot = bid >> 3;   // slot 0..63
  const int m0 = (xcd + 8 * (slot >> 4)) * 128;  // 32 panels over 8 XCDs
  const int n0 = (slot & 15) * 64;

  const int sr = t >> 2;
  const int sc = (t & 3) * 16;

  v8s ar[4], br[2];
  auto loadA = [&](int kc) {
#pragma unroll
    for (int rr = 0; rr < 2; ++rr) {
      const bf16* p = A + (size_t)(m0 + sr + rr * 64) * DIMM + kc + sc;
#pragma unroll
      for (int i = 0; i < 2; ++i) ar[rr * 2 + i] = ((const v8s*)p)[i];
    }
  };
  auto loadB = [&](int kc) {
    const bf16* p = W + (size_t)(n0 + sr) * DIMM + kc + sc;
#pragma unroll
    for (int i = 0; i < 2; ++i) br[i] = ((const v8s*)p)[i];
  };

  f32x4 acc[4][2] = {};
  loadA(0);
  loadB(0);
  for (int kc = 0; kc < DIMM; kc += 64) {
    __syncthreads();
#pragma unroll
    for (int rr = 0; rr < 2; ++rr) {
      *(v8s*)&As[sr + rr * 64][sc] = ar[rr * 2 + 0];
      *(v8s*)&As[sr + rr * 64][sc + 8] = ar[rr * 2 + 1];
    }
    *(v8s*)&Bs[sr][sc] = br[0];
    *(v8s*)&Bs[sr][sc + 8] = br[1];
    if (kc + 64 < DIMM) {
      loadA(kc + 64);
      loadB(kc + 64);
    }
    __syncthreads();
#pragma unroll
    for (int ks = 0; ks < 2; ++ks) {
      v8s af[4], bfr[2];
#pragma unroll
      for (int i = 0; i < 4; ++i)
        af[i] = *(const v8s*)&As[wm + i * 16 + l15][ks * 32 + quad * 8];
#pragma unroll
      for (int j = 0; j < 2; ++j)
        bfr[j] = *(const v8s*)&Bs[wn + j * 16 + l15][ks * 32 + quad * 8];
#pragma unroll
      for (int i = 0; i < 4; ++i)
#pragma unroll
        for (int j = 0; j < 2; ++j)
          acc[i][j] = __builtin_amdgcn_mfma_f32_16x16x32_bf16(
              af[i], bfr[j], acc[i][j], 0, 0, 0);
    }
  }

#pragma unroll
  for (int i = 0; i < 4; ++i) {
#pragma unroll
    for (int r = 0; r < 4; ++r) {
      const int m = m0 + wm + i * 16 + quad * 4 + r;
#pragma unroll
      for (int j = 0; j < 2; ++j) {
        const int n = n0 + wn + j * 16 + l15;
        out[(size_t)m * DIMM + n] = acc[i][j][r];
      }
    }
  }
}

// ---------------------------------------------------------------------------
// MFMA flash attention v7 EXACT (best measured: 56.5-57.4us).  R4/R5/R7/R8
// all regressed it; do not touch the inner loop.
// ---------------------------------------------------------------------------
__global__ __launch_bounds__(512) void attn_kernel(
    const bf16* __restrict__ Qr, const bf16* __restrict__ Kr,
    const bf16* __restrict__ Vt, const unsigned long long* __restrict__ mp,
    bf16* __restrict__ Ar) {
  // smem[0] = K tiles, smem[1] = V tiles; [kv][parity][buf][row][col]
  __shared__ __align__(16) bf16 smem[2][2][2][64][72];

  const int t = threadIdx.x;
  const int wave = t >> 6, lane = t & 63;
  const int l31 = lane & 31, hf = lane >> 5;
  const int qb = wave & 3;   // q sub-block 0..3 (32 rows each)
  const int pr = wave >> 2;  // kt parity: 0 = even kt, 1 = odd kt

  const int bx = blockIdx.x;
  const int xcd = bx & 7, j = bx >> 3;
  const int g = (xcd << 2) | (j & 3);  // (b,h) group 0..31
  const int tile = j >> 2;             // q-tile 0..15 (128 rows each)
  const int hd = g & 15, b = g >> 4;

  const int qw = tile * 128 + qb * 32;  // wave owns 32 q-rows
  const size_t bhv = ((size_t)b * HH + hd) * DKK;

  // Q as B-fragments: lane l31 = q-col, c = cs*16 + 8*hf + i
  v8s bq[4];
  {
    const bf16* qrow = Qr + ((size_t)(b * SS + qw + l31)) * DIMM + hd * 64;
#pragma unroll
    for (int cs = 0; cs < 4; ++cs)
      bq[cs] = *(const v8s*)(qrow + cs * 16 + 8 * hf);
  }

  // ones B-fragment for row-sum MFMA
  v8s vones;
#pragma unroll
  for (int i = 0; i < 8; ++i) vones[i] = (short)0x3F80;

  f32x16 o0 = {}, o1 = {}, ol = {};

  // cooperative staging: 512 threads x 16B per tile, 4 tiles per step
  const int r0 = t >> 3;       // 0..63
  const int c0 = (t & 7) * 8;  // 0..56

  auto gK = [&](int kt) {
    return *(const v8s*)(Kr + ((size_t)(b * SS + kt * 64 + r0)) * DIMM +
                         hd * 64 + c0);
  };
  auto gV = [&](int kt) {
    return *(const v8s*)(Vt + (bhv + r0) * SS + kt * 64 + c0);
  };
  auto loadM = [&](int kt) {
    return mp[((size_t)b * 32 + kt) * SS + qw + l31];
  };

  // prologue: stage kt 0 (par0 buf0) and kt 1 (par1 buf0); prefetch kt 2,3
  {
    const v8s k0 = gK(0), v0 = gV(0), k1 = gK(1), v1 = gV(1);
    *(v8s*)&smem[0][0][0][r0][c0] = k0;
    *(v8s*)&smem[1][0][0][r0][c0] = v0;
    *(v8s*)&smem[0][1][0][r0][c0] = k1;
    *(v8s*)&smem[1][1][0][r0][c0] = v1;
  }
  v8s kpr[2], vpr[2];
  kpr[0] = gK(2);
  vpr[0] = gV(2);
  kpr[1] = gK(3);
  vpr[1] = gV(3);
  unsigned long long mwcur = loadM(pr);

  for (int s = 0; s < 16; ++s) {
    __syncthreads();
    const int nb = (s + 1) & 1;
    if (s < 15) {
      *(v8s*)&smem[0][0][nb][r0][c0] = kpr[0];
      *(v8s*)&smem[1][0][nb][r0][c0] = vpr[0];
      *(v8s*)&smem[0][1][nb][r0][c0] = kpr[1];
      *(v8s*)&smem[1][1][nb][r0][c0] = vpr[1];
      if (s < 14) {
        kpr[0] = gK(2 * s + 4);
        vpr[0] = gV(2 * s + 4);
        kpr[1] = gK(2 * s + 5);
        vpr[1] = gV(2 * s + 5);
      }
    }
    const unsigned long long mwnext = (s < 15) ? loadM(2 * s + 2 + pr) : 0ULL;
    const unsigned long long mq = mwcur >> (4 * hf);
    const int cb = s & 1;

    // ---- QK^T (swapped): st[n] rows = k (n*32 block), col = q = l31 ----
    f32x16 st[2];
#pragma unroll
    for (int n = 0; n < 2; ++n) {
      f32x16 sa = {};
#pragma unroll
      for (int cs = 0; cs < 4; ++cs) {
        const v8s ak =
            *(const v8s*)&smem[0][pr][cb][n * 32 + l31][cs * 16 + 8 * hf];
        sa = __builtin_amdgcn_mfma_f32_32x32x16_bf16(ak, bq[cs], sa, 0, 0, 0);
      }
      st[n] = sa;
    }

    // ---- masked exp2 + pack to bf16 pairs (in-register) ----
    int pd[8][2];
#pragma unroll
    for (int n = 0; n < 2; ++n)
#pragma unroll
      for (int g2 = 0; g2 < 4; ++g2)
#pragma unroll
        for (int jj = 0; jj < 2; ++jj) {
          const int bp = 32 * n + 8 * g2 + 2 * jj;
          const int m = g2 * 4 + 2 * jj;
          const float p0 =
              ((mq >> bp) & 1) ? __builtin_amdgcn_exp2f(st[n][m]) : 0.f;
          const float p1 =
              ((mq >> (bp + 1)) & 1) ? __builtin_amdgcn_exp2f(st[n][m + 1])
                                     : 0.f;
          pd[n * 4 + g2][jj] = cvt_pk_bf16(p0, p1);
        }

    // ---- redistribute to PV A-fragments: 2 permlane32_swap per k-slice ----
    v8s af[4];
#pragma unroll
    for (int ks = 0; ks < 4; ++ks) {
      int a0 = pd[2 * ks][0], b0 = pd[2 * ks + 1][0];
      int a1 = pd[2 * ks][1], b1 = pd[2 * ks + 1][1];
      asm("v_permlane32_swap_b32 %0, %1" : "+v"(a0), "+v"(b0));
      asm("v_permlane32_swap_b32 %0, %1" : "+v"(a1), "+v"(b1));
      int4 w;
      w.x = a0;
      w.y = a1;
      w.z = b0;
      w.w = b1;
      af[ks] = *(v8s*)&w;
    }

    // ---- PV + row-sum ----
#pragma unroll
    for (int ks = 0; ks < 4; ++ks) {
      const v8s bv0 = *(const v8s*)&smem[1][pr][cb][l31][ks * 16 + 8 * hf];
      const v8s bv1 =
          *(const v8s*)&smem[1][pr][cb][32 + l31][ks * 16 + 8 * hf];
      o0 = __builtin_amdgcn_mfma_f32_32x32x16_bf16(af[ks], bv0, o0, 0, 0, 0);
      o1 = __builtin_amdgcn_mfma_f32_32x32x16_bf16(af[ks], bv1, o1, 0, 0, 0);
      ol = __builtin_amdgcn_mfma_f32_32x32x16_bf16(af[ks], vones, ol, 0, 0, 0);
    }
    mwcur = mwnext;
  }

  // ---- cross-parity combine via LDS (exact sum; no running max) ----
  // scratch overlays the (now dead) K/V staging; stride 52 f32 (16B-aligned,
  // 8-bank spread) per lane.
  __syncthreads();
  float* scratch = (float*)&smem[0][0][0][0][0];
  if (wave >= 4) {
    float* dst = scratch + ((size_t)(wave - 4) * 64 + lane) * 52;
#pragma unroll
    for (int i = 0; i < 4; ++i) {
      f32x4 t0 = {o0[4 * i], o0[4 * i + 1], o0[4 * i + 2], o0[4 * i + 3]};
      f32x4 t1 = {o1[4 * i], o1[4 * i + 1], o1[4 * i + 2], o1[4 * i + 3]};
      f32x4 t2 = {ol[4 * i], ol[4 * i + 1], ol[4 * i + 2], ol[4 * i + 3]};
      *(f32x4*)(dst + 4 * i) = t0;
      *(f32x4*)(dst + 16 + 4 * i) = t1;
      *(f32x4*)(dst + 32 + 4 * i) = t2;
    }
  }
  __syncthreads();
  if (wave < 4) {
    const float* src = scratch + ((size_t)wave * 64 + lane) * 52;
#pragma unroll
    for (int m = 0; m < 16; ++m) {
      o0[m] += src[m];
      o1[m] += src[16 + m];
      ol[m] += src[32 + m];
    }
    // ---- epilogue: normalize rows and store flat [q][hd*64 + d] ----
#pragma unroll
    for (int m = 0; m < 16; ++m) {
      const float inv = __builtin_amdgcn_rcpf(ol[m]);
      const int q = qw + (m & 3) + 8 * (m >> 2) + 4 * hf;
      const size_t row = (size_t)b * SS + q;
      Ar[row * DIMM + hd * 64 + l31] = __float2bfloat16(o0[m] * inv);
      Ar[row * DIMM + hd * 64 + 32 + l31] = __float2bfloat16(o1[m] * inv);
    }
  }
}

extern "C" void kernel_launch(void* const* d_in, const int* in_sizes, int n_in,
                              void* d_out, int out_size, void* d_ws,
                              size_t ws_size, hipStream_t stream) {
  const float* dec = (const float*)d_in[0];
  const float* enc = (const float*)d_in[1];
  const float* Wq = (const float*)d_in[2];
  const float* Wkv = (const float*)d_in[3];
  const float* Wo = (const float*)d_in[4];
  const int* mask = (const int*)d_in[5];
  float* out = (float*)d_out;

  // decb/Wqb live in d_out: dead scratch until out_gemm overwrites it.
  bf16* decb = (bf16*)d_out;
  bf16* Wqb = (bf16*)((char*)d_out + ((size_t)2 * SS * DIMM * 2));

  // ws layout (40.4 MB): encb 8 MiB (Ar overlays) | Wkvb 4 | Wob 2 |
  // Qr 8 | Kr 8 | Vt 8 | mp 1
  char* ws = (char*)d_ws;
  size_t off = 0;
  bf16* encb = (bf16*)(ws + off);
  bf16* Ar = (bf16*)(ws + off);   off += (size_t)2 * SS * DIMM * 2;
  bf16* Wkvb = (bf16*)(ws + off); off += (size_t)2 * DIMM * DIMM * 2;
  bf16* Wob = (bf16*)(ws + off);  off += (size_t)DIMM * DIMM * 2;
  bf16* Qr = (bf16*)(ws + off);   off += (size_t)2 * SS * DIMM * 2;
  bf16* Kr = (bf16*)(ws + off);   off += (size_t)2 * SS * DIMM * 2;
  bf16* Vt = (bf16*)(ws + off);   off += (size_t)2 * SS * DIMM * 2;
  unsigned long long* mp = (unsigned long long*)(ws + off);

  dim3 blk(256);
  convert_pack_kernel<<<dim3(1024), blk, 0, stream>>>(
      dec, enc, Wq, Wkv, Wo, mask, decb, encb, Wqb, Wkvb, Wob, mp);
  proj_gemm_kernel<<<dim3(768), blk, 0, stream>>>(decb, encb, Wqb, Wkvb, Qr,
                                                  Kr, Vt);
  attn_kernel<<<dim3(512), dim3(512), 0, stream>>>(Qr, Kr, Vt, mp, Ar);
  out_gemm_kernel<<<dim3(512), blk, 0, stream>>>(Ar, Wob, out);
}